// Round 9
// baseline (192.733 us; speedup 1.0000x reference)
//
#include <hip/hip_runtime.h>

typedef __attribute__((ext_vector_type(8))) short short8;
typedef __attribute__((ext_vector_type(4))) float f32x4;
typedef unsigned short u16;
typedef unsigned int u32;

// b=16, C=256, n=4096(64x64), HEADS=4, D=32, hidden=128
// y = G[b] . x + b_out  with  G[b] = W_out . C_bd[b] . W_q
// Pipeline (4 dispatches): fused[transpose+kv GEMM+exp/ctx] -> red -> G -> y.
// The (nt,b) x-slab is transposed into LDS once, consumed by the kv GEMM from LDS
// (B-panel resident, K=256 in 64KB), and simultaneously written to global xT for k_y.

__device__ __forceinline__ u16 f2bf(float f) {
    u32 x = __float_as_uint(f);
    u32 r = (x + 0x7fffu + ((x >> 16) & 1u)) >> 16;
    return (u16)r;
}
__device__ __forceinline__ float bf2f(u16 h) {
    return __uint_as_float(((u32)h) << 16);
}

// pack 8 fp32 -> 8 bf16 (RNE) via v_cvt_pk_bf16_f32 (no builtin on gfx950; low half = src0)
__device__ __forceinline__ short8 pack_bf16x8(const float* f) {
    union { u32 w[4]; short8 s; } u;
#pragma unroll
    for (int i = 0; i < 4; i++)
        asm("v_cvt_pk_bf16_f32 %0, %1, %2" : "=v"(u.w[i]) : "v"(f[2 * i]), "v"(f[2 * i + 1]));
    return u.s;
}

typedef __attribute__((address_space(1))) u32 as1_u32;
typedef __attribute__((address_space(3))) u32 as3_u32;
__device__ __forceinline__ void gload16(const void* g, void* l) {
    // async 16B global -> LDS (dest = wave-uniform base + lane*16)
    __builtin_amdgcn_global_load_lds((as1_u32*)g, (as3_u32*)l, 16, 0, 0);
}

// ---------------- K1: fused transpose + kv GEMM (BM=256,BN=128,K=256) + exp/den + ctx ----------
// grid (nt=32, b=16), 512 threads (8 waves). LDS 74 KB -> 2 blocks/CU.
// sX layout: [n 0..127][granule g 0..31] with g ^= (n&7); 8 u16 per granule. MFMA ds_read_b128
// then hits 2 lanes/bank (free). W (A-operand) fragments read fp32 from L2 + cvt_pk in-reg.
__global__ __launch_bounds__(512, 4) void k_fused(const float* __restrict__ x,
                                                  const float* __restrict__ W,
                                                  u16* __restrict__ xT,
                                                  float* __restrict__ part,
                                                  float* __restrict__ denp) {
    __shared__ alignas(16) char smem[74752];
    u16* sX   = (u16*)smem;                  // [128][256] granule-swizzled bf16 x^T slab
    u16* tile = (u16*)(smem + 65536);        // [64][72] transpose scratch (r7-proven pattern)
    u16* Pl   = (u16*)smem;                  // overlay after GEMM: [128][136] exp(k)
    u16* Vl   = (u16*)(smem + 34816);        // overlay after GEMM: [128][136] v
    float* dpart = (float*)(smem + 69632);   // [128][2] den partials (tile region, dead by then)

    int t = threadIdx.x;
    int nt = blockIdx.x, b = blockIdx.y;
    int n0 = nt * 128;
    int lane = t & 63, wv = t >> 6, l16 = lane & 15, lq = lane >> 4;
    int wr = wv >> 1, wc = wv & 1;

    // ---- phase 1: transpose x[b][:, n-slab] -> sX (and global xT), 8 sub-tiles of 64c x 64n ----
    for (int si = 0; si < 8; si++) {
        int cq = (si & 3) * 64, nh = (si >> 2) * 64;
        __syncthreads();                     // protect tile reuse from previous iteration
#pragma unroll
        for (int i = 0; i < 2; i++) {        // 1a: 64x64 fp32 -> tile (swizzled), coalesced reads
            int idx = i * 512 + t;           // 0..1023
            int cl = idx >> 4, nq = (idx & 15) * 4;
            float4 v = *reinterpret_cast<const float4*>(
                x + ((size_t)(b * 256 + cq + cl) * 4096 + n0 + nh + nq));
            u32 w0 = (u32)f2bf(v.x) | ((u32)f2bf(v.y) << 16);
            u32 w1 = (u32)f2bf(v.z) | ((u32)f2bf(v.w) << 16);
            uint2 o = {w0, w1};
            int col = nq ^ (((cl >> 3) & 7) << 3);
            *reinterpret_cast<uint2*>(&tile[cl * 72 + col]) = o;
        }
        __syncthreads();
        {                                    // 1b: gather transposed (2-way banks), store xT + sX
            int nl = t >> 3, c8 = (t & 7) * 8;   // nl 0..63, c8 0..56
            alignas(16) u16 vals[8];
#pragma unroll
            for (int j = 0; j < 8; j++) {
                int row = c8 + j;
                vals[j] = tile[row * 72 + (nl ^ (((row >> 3) & 7) << 3))];
            }
            *reinterpret_cast<uint4*>(xT + ((size_t)(b * 4096 + n0 + nh + nl) * 256 + cq + c8)) =
                *reinterpret_cast<const uint4*>(vals);
            int nloc = nh + nl;
            int g = (cq + c8) >> 3;          // global c-granule 0..31
            *reinterpret_cast<uint4*>(&sX[(nloc * 32 + (g ^ (nloc & 7))) * 8]) =
                *reinterpret_cast<const uint4*>(vals);
        }
    }
    __syncthreads();

    // ---- kv GEMM: acc[o][n] = sum_c W[128+o][c] * x[c][n];  barrier-free (B resident in LDS) ----
    f32x4 acc[4][4];
#pragma unroll
    for (int i = 0; i < 4; i++)
#pragma unroll
        for (int j = 0; j < 4; j++) acc[i][j] = (f32x4){0.f, 0.f, 0.f, 0.f};

    const float* Wsrc = W + 128 * 256;       // k,v weight rows (fp32, L2-resident)
    for (int kc = 0; kc < 4; kc++) {
#pragma unroll
        for (int ks = 0; ks < 2; ks++) {
            int col = kc * 64 + ks * 32 + lq * 8;
            int g = col >> 3;
            short8 af[4], bfr[4];
#pragma unroll
            for (int i = 0; i < 4; i++) {
                const float* wp = Wsrc + (size_t)(wr * 64 + i * 16 + l16) * 256 + col;
                float4 wa = *reinterpret_cast<const float4*>(wp);
                float4 wb = *reinterpret_cast<const float4*>(wp + 4);
                float f8[8] = {wa.x, wa.y, wa.z, wa.w, wb.x, wb.y, wb.z, wb.w};
                af[i] = pack_bf16x8(f8);
            }
#pragma unroll
            for (int j = 0; j < 4; j++) {
                int n = wc * 64 + j * 16 + l16;
                bfr[j] = *reinterpret_cast<const short8*>(&sX[(n * 32 + (g ^ (n & 7))) * 8]);
            }
#pragma unroll
            for (int i = 0; i < 4; i++)
#pragma unroll
                for (int j = 0; j < 4; j++)
                    acc[i][j] = __builtin_amdgcn_mfma_f32_16x16x32_bf16(af[i], bfr[j], acc[i][j], 0, 0, 0);
        }
    }
    __syncthreads();   // all sX reads done; safe to overlay Pl/Vl

    // ---- epilogue: P = exp(k) -> Pl, den partials; V -> Vl (m rows 0..127 = k, 128..255 = v) ----
    if (wr < 2) {
#pragma unroll
        for (int i = 0; i < 4; i++) {
            int rbase = wr * 64 + i * 16 + lq * 4;
            float srow[4] = {0.f, 0.f, 0.f, 0.f};
#pragma unroll
            for (int j = 0; j < 4; j++) {
                int n = wc * 64 + j * 16 + l16;
#pragma unroll
                for (int rr = 0; rr < 4; rr++) {
                    float e = __expf(acc[i][j][rr]);
                    Pl[(rbase + rr) * 136 + n] = f2bf(e);
                    srow[rr] += e;
                }
            }
#pragma unroll
            for (int rr = 0; rr < 4; rr++) {
                float s = srow[rr];
                s += __shfl_xor(s, 1, 64); s += __shfl_xor(s, 2, 64);
                s += __shfl_xor(s, 4, 64); s += __shfl_xor(s, 8, 64);
                if (l16 == 0) dpart[(rbase + rr) * 2 + wc] = s;
            }
        }
    } else {
#pragma unroll
        for (int i = 0; i < 4; i++) {
            int rbase = (wr - 2) * 64 + i * 16 + lq * 4;
#pragma unroll
            for (int j = 0; j < 4; j++) {
                int n = wc * 64 + j * 16 + l16;
#pragma unroll
                for (int rr = 0; rr < 4; rr++)
                    Vl[(rbase + rr) * 136 + n] = f2bf(acc[i][j][rr]);
            }
        }
    }
    __syncthreads();

    // ---- ctx GEMM: per head h: C_part[d][e] = sum_n P[h*32+d][n] * V[h*32+e][n] (K=128) ----
    int h = wv >> 1, eh = wv & 1;
    f32x4 a2[2];
    a2[0] = (f32x4){0.f, 0.f, 0.f, 0.f};
    a2[1] = (f32x4){0.f, 0.f, 0.f, 0.f};
#pragma unroll
    for (int kk = 0; kk < 4; kk++) {
        int col = kk * 32 + lq * 8;
        short8 bfr = *reinterpret_cast<const short8*>(&Vl[(h * 32 + eh * 16 + l16) * 136 + col]);
#pragma unroll
        for (int i = 0; i < 2; i++) {
            short8 af = *reinterpret_cast<const short8*>(&Pl[(h * 32 + i * 16 + l16) * 136 + col]);
            a2[i] = __builtin_amdgcn_mfma_f32_16x16x32_bf16(af, bfr, a2[i], 0, 0, 0);
        }
    }
    float* pp = part + ((size_t)(b * 32 + nt) * 4 + h) * 1024;
#pragma unroll
    for (int i = 0; i < 2; i++)
#pragma unroll
        for (int rr = 0; rr < 4; rr++)
            pp[(i * 16 + lq * 4 + rr) * 32 + eh * 16 + l16] = a2[i][rr];

    if (t < 128)
        denp[((size_t)b * 128 + t) * 32 + nt] = dpart[t * 2] + dpart[t * 2 + 1];
}

// ---------------- K2: reduce 32 ctx partials + divide by den -> C[bh][d][e] fp32 ----------------
// grid (bh=64, seg=4): each block handles 256 de of the 1024-slab. nt-ascending order.
__global__ __launch_bounds__(256) void k_red(const float* __restrict__ part,
                                             const float* __restrict__ denp,
                                             float* __restrict__ C) {
    __shared__ float invd[32];
    int bh = blockIdx.x, seg = blockIdx.y;
    int b = bh >> 2, h = bh & 3;
    int t = threadIdx.x;
    if (t < 32) {
        const float* dp = denp + ((size_t)b * 128 + h * 32 + t) * 32;
        float s = 0.f;
#pragma unroll
        for (int nt = 0; nt < 32; nt++) s += dp[nt];
        invd[t] = 1.0f / s;
    }
    __syncthreads();
    int de = seg * 256 + t;               // [0, 1024)
    float a = 0.f;
#pragma unroll 8
    for (int nt = 0; nt < 32; nt++)
        a += part[((size_t)(b * 32 + nt) * 4 + h) * 1024 + de];
    C[(size_t)bh * 1024 + de] = a * invd[de >> 5];
}

// ---------------- K3: G[b] = W_out . C_bd[b] . W_q  -> bf16 (W_q fp32 rows 0..127) ----------
// grid (b=16, ot=16, ch=2): 16 o-rows per block, 128 c columns per block.
__global__ __launch_bounds__(256) void k_G(const float* __restrict__ C,
                                           const float* __restrict__ Wout,
                                           const float* __restrict__ Wqkv,  // rows 0..127 = W_q
                                           u16* __restrict__ Gb) {
    __shared__ float Cs[4096];    // [h][d][e]
    __shared__ float Us[2048];    // [ol][he]
    int b = blockIdx.x, ot = blockIdx.y, ch = blockIdx.z, t = threadIdx.x;
    int o0 = ot * 16;
#pragma unroll
    for (int q = 0; q < 16; q++) {
        int idx = q * 256 + t;
        Cs[idx] = C[(size_t)b * 4096 + idx];
    }
    __syncthreads();
#pragma unroll
    for (int q = 0; q < 8; q++) {
        int idx = q * 256 + t;          // ol*128 + he
        int ol = idx >> 7, he = idx & 127;
        int h = he >> 5, e = he & 31;
        const float* wrow = Wout + (o0 + ol) * 128 + h * 32;
        const float* crow = &Cs[h * 1024 + e];
        float a = 0.f;
#pragma unroll
        for (int d = 0; d < 32; d++) a += wrow[d] * crow[d * 32];
        Us[idx] = a;
    }
    __syncthreads();
    int ol = t >> 4, c0 = ch * 128 + (t & 15) * 8;
    float acc[8];
#pragma unroll
    for (int cc = 0; cc < 8; cc++) acc[cc] = 0.f;
    const float* Ur = &Us[ol * 128];
#pragma unroll 4
    for (int he = 0; he < 128; he++) {
        float u = Ur[he];
        const float* wqp = Wqkv + (size_t)he * 256 + c0;
        float4 wa = *reinterpret_cast<const float4*>(wqp);
        float4 wb = *reinterpret_cast<const float4*>(wqp + 4);
        acc[0] += u * wa.x; acc[1] += u * wa.y; acc[2] += u * wa.z; acc[3] += u * wa.w;
        acc[4] += u * wb.x; acc[5] += u * wb.y; acc[6] += u * wb.z; acc[7] += u * wb.w;
    }
    alignas(16) u16 ob[8];
#pragma unroll
    for (int cc = 0; cc < 8; cc++) ob[cc] = f2bf(acc[cc]);
    *reinterpret_cast<uint4*>(Gb + (size_t)(b * 256 + o0 + ol) * 256 + c0) =
        *reinterpret_cast<const uint4*>(ob);
}

// ---------------- K4: y = G[b].x + bias, BM=256 x BN=128, K=256, xT slab read ONCE ----------
// grid (nt=32, b=16), 512 threads (8 waves, 4M x 2N).
__global__ __launch_bounds__(512, 4) void k_y(const u16* __restrict__ Gb,
                                              const u16* __restrict__ xT,
                                              const float* __restrict__ bout,
                                              float* __restrict__ y) {
    __shared__ alignas(16) u16 sA[256 * 64];
    __shared__ alignas(16) u16 sB[128 * 64];
    int t = threadIdx.x;
    int nt = blockIdx.x, b = blockIdx.y;
    int n0 = nt * 128;
    int lane = t & 63, wv = t >> 6, l16 = lane & 15, lq = lane >> 4;
    int wr = wv >> 1, wc = wv & 1;
    int trow = t >> 3, tc8 = (t & 7) * 8;

    f32x4 acc[4][4];
#pragma unroll
    for (int i = 0; i < 4; i++)
#pragma unroll
        for (int j = 0; j < 4; j++) acc[i][j] = (f32x4){0.f, 0.f, 0.f, 0.f};

    const u16* Asrc = Gb + (size_t)b * 256 * 256;
    const u16* Bsrc = xT + (size_t)(b * 4096 + n0) * 256;

    for (int kc = 0; kc < 4; kc++) {
        __syncthreads();
#pragma unroll
        for (int q = 0; q < 4; q++) {       // A: 256 rows x 64 c (linear in t)
            int row = q * 64 + trow;
            gload16(Asrc + (size_t)row * 256 + kc * 64 + tc8, &sA[row * 64 + tc8]);
        }
#pragma unroll
        for (int q = 0; q < 2; q++) {       // B: 128 rows x 64 c
            int row = q * 64 + trow;
            gload16(Bsrc + (size_t)row * 256 + kc * 64 + tc8, &sB[row * 64 + tc8]);
        }
        __syncthreads();
#pragma unroll
        for (int ks = 0; ks < 2; ks++) {
            int col = ks * 32 + lq * 8;
            short8 af[4], bfr[4];
#pragma unroll
            for (int i = 0; i < 4; i++)
                af[i] = *reinterpret_cast<const short8*>(&sA[(wr * 64 + i * 16 + l16) * 64 + col]);
#pragma unroll
            for (int j = 0; j < 4; j++)
                bfr[j] = *reinterpret_cast<const short8*>(&sB[(wc * 64 + j * 16 + l16) * 64 + col]);
#pragma unroll
            for (int i = 0; i < 4; i++)
#pragma unroll
                for (int j = 0; j < 4; j++)
                    acc[i][j] = __builtin_amdgcn_mfma_f32_16x16x32_bf16(af[i], bfr[j], acc[i][j], 0, 0, 0);
        }
    }
#pragma unroll
    for (int i = 0; i < 4; i++) {
        int obase = wr * 64 + i * 16 + lq * 4;
#pragma unroll
        for (int j = 0; j < 4; j++) {
            int n = n0 + wc * 64 + j * 16 + l16;
#pragma unroll
            for (int rr = 0; rr < 4; rr++) {
                int o = obase + rr;
                y[(size_t)(b * 256 + o) * 4096 + n] = acc[i][j][rr] + bout[o];
            }
        }
    }
}

extern "C" void kernel_launch(void* const* d_in, const int* in_sizes, int n_in,
                              void* d_out, int out_size, void* d_ws, size_t ws_size,
                              hipStream_t stream) {
    const float* x    = (const float*)d_in[0];
    const float* Wqkv = (const float*)d_in[1];
    const float* Wout = (const float*)d_in[2];
    const float* bout = (const float*)d_in[3];
    float* y = (float*)d_out;

    char* ws = (char*)d_ws;
    u16*   xT   = (u16*)(ws);                     // 32 MB   [b][n][c] bf16
    float* part = (float*)(ws + 33554432);        // 8 MB    ctx partials [b][nt][h][1024]
    float* denp = (float*)(ws + 41943040);        // 256 KB  den partials [b*128+row][nt]
    float* C    = (float*)(ws + 42205184);        // 256 KB  [bh][d][e] fp32
    u16*   Gb   = (u16*)(ws + 42467328);          // 2 MB    [b][256][256] bf16

    k_fused<<<dim3(32, 16), 512, 0, stream>>>(x, Wqkv, xT, part, denp);
    k_red  <<<dim3(64, 4), 256, 0, stream>>>(part, denp, C);
    k_G    <<<dim3(16, 16, 2), 256, 0, stream>>>(C, Wout, Wqkv, Gb);
    k_y    <<<dim3(32, 16), 512, 0, stream>>>(Gb, xT, bout, y);
}

// Round 10
// 170.179 us; speedup vs baseline: 1.1325x; 1.1325x over previous
//
#include <hip/hip_runtime.h>

typedef __attribute__((ext_vector_type(8))) short short8;
typedef __attribute__((ext_vector_type(4))) float f32x4;
typedef unsigned short u16;
typedef unsigned int u32;

// b=16, C=256, n=4096(64x64), HEADS=4, D=32, hidden=128
// y = G[b] . x + b_out  with  G[b] = W_out . C_bd[b] . W_q
// Pipeline: transpose(+Wconv) -> fused kv+ctx -> red -> G -> y.   (round-7 verified config)

__device__ __forceinline__ u16 f2bf(float f) {
    u32 x = __float_as_uint(f);
    u32 r = (x + 0x7fffu + ((x >> 16) & 1u)) >> 16;
    return (u16)r;
}
__device__ __forceinline__ float bf2f(u16 h) {
    return __uint_as_float(((u32)h) << 16);
}

typedef __attribute__((address_space(1))) u32 as1_u32;
typedef __attribute__((address_space(3))) u32 as3_u32;
__device__ __forceinline__ void gload16(const void* g, void* l) {
    // async 16B global -> LDS (dest = wave-uniform base + lane*16)
    __builtin_amdgcn_global_load_lds((as1_u32*)g, (as3_u32*)l, 16, 0, 0);
}

// ---------------- K0: transpose x[b][c][n] fp32 -> xT[b][n][c] bf16;  + W conv folded in ------
// LDS tile column-XOR-swizzled: col ^= ((row>>3)&7)<<3  (write AND read) -> gather reads 2-way.
__global__ __launch_bounds__(256) void k_transpose(const float* __restrict__ x,
                                                   u16* __restrict__ xT,
                                                   const float* __restrict__ W,
                                                   u16* __restrict__ Wb) {
    __shared__ alignas(16) u16 tile[64 * 72];
    int t = threadIdx.x;
    int n0 = blockIdx.x * 64, c0 = blockIdx.y * 64, b = blockIdx.z;

    // ---- folded W_qkv fp32 -> bf16 conversion (96 chunks of 1024 floats) ----
    int flat = (b * 4 + blockIdx.y) * 64 + blockIdx.x;
    if (flat < 96) {
        int idx = flat * 256 + t;
        float4 v = *reinterpret_cast<const float4*>(W + (size_t)idx * 4);
        u32 w0 = (u32)f2bf(v.x) | ((u32)f2bf(v.y) << 16);
        u32 w1 = (u32)f2bf(v.z) | ((u32)f2bf(v.w) << 16);
        uint2 o = {w0, w1};
        *reinterpret_cast<uint2*>(Wb + (size_t)idx * 4) = o;
    }

    int rr = t >> 4, nq = (t & 15) * 4;
#pragma unroll
    for (int i = 0; i < 4; i++) {
        int cl = i * 16 + rr;
        float4 v = *reinterpret_cast<const float4*>(x + ((size_t)(b * 256 + c0 + cl) * 4096 + n0 + nq));
        u32 w0 = (u32)f2bf(v.x) | ((u32)f2bf(v.y) << 16);
        u32 w1 = (u32)f2bf(v.z) | ((u32)f2bf(v.w) << 16);
        uint2 o = {w0, w1};
        int col = nq ^ (((cl >> 3) & 7) << 3);
        *reinterpret_cast<uint2*>(&tile[cl * 72 + col]) = o;
    }
    __syncthreads();
    int r = t >> 3, c8 = (t & 7) * 8;
#pragma unroll
    for (int i = 0; i < 2; i++) {
        int nl = i * 32 + r;
        alignas(16) u16 vals[8];
#pragma unroll
        for (int j = 0; j < 8; j++) {
            int row = c8 + j;
            vals[j] = tile[row * 72 + (nl ^ (((row >> 3) & 7) << 3))];
        }
        *reinterpret_cast<uint4*>(xT + ((size_t)(b * 4096 + n0 + nl) * 256 + c0 + c8)) =
            *reinterpret_cast<const uint4*>(vals);
    }
}

// ---------------- K1: fused kv GEMM (BM=256,BN=128,K=256) + exp/den + ctx partials ----------
// grid (nt=32, b=16), 512 threads (8 waves). Both operands via global_load_lds. 2 blocks/CU.
__global__ __launch_bounds__(512, 4) void k_fused(const u16* __restrict__ xT,
                                                  const u16* __restrict__ Wb,
                                                  float* __restrict__ part,
                                                  float* __restrict__ denp) {
    __shared__ alignas(16) char smem[70656];
    u16* sA = (u16*)smem;                   // [256 m][64]  per-kc chunk (linear, gload16)
    u16* sB = (u16*)(smem + 32768);         // [128 n][64]  per-kc chunk (linear, gload16)
    u16* Pl = (u16*)smem;                   // overlay: [128][136] exp(k) bf16
    u16* Vl = (u16*)(smem + 34816);         // overlay: [128][136] v bf16
    float* dpart = (float*)(smem + 69632);  // [128][2] den partials

    int t = threadIdx.x;
    int nt = blockIdx.x, b = blockIdx.y;
    int n0 = nt * 128;
    int lane = t & 63, wv = t >> 6, l16 = lane & 15, lq = lane >> 4;
    int wr = wv >> 1, wc = wv & 1;
    int trow = t >> 3, tc8 = (t & 7) * 8;

    f32x4 acc[4][4];
#pragma unroll
    for (int i = 0; i < 4; i++)
#pragma unroll
        for (int j = 0; j < 4; j++) acc[i][j] = (f32x4){0.f, 0.f, 0.f, 0.f};

    const u16* Asrc = Wb + 128 * 256;       // k,v weight rows
    const u16* Bsrc = xT + (size_t)(b * 4096 + n0) * 256;

    for (int kc = 0; kc < 4; kc++) {
        __syncthreads();
#pragma unroll
        for (int q = 0; q < 4; q++) {       // A: 256 rows x 64 c, LDS off = q*8192 + t*16 (linear)
            int row = q * 64 + trow;
            gload16(Asrc + (size_t)row * 256 + kc * 64 + tc8, &sA[row * 64 + tc8]);
        }
#pragma unroll
        for (int q = 0; q < 2; q++) {       // B: 128 rows x 64 c
            int row = q * 64 + trow;
            gload16(Bsrc + (size_t)row * 256 + kc * 64 + tc8, &sB[row * 64 + tc8]);
        }
        __syncthreads();                    // drains vmcnt before fragment reads
#pragma unroll
        for (int ks = 0; ks < 2; ks++) {
            int col = ks * 32 + lq * 8;
            short8 af[4], bfr[4];
#pragma unroll
            for (int i = 0; i < 4; i++)
                af[i] = *reinterpret_cast<const short8*>(&sA[(wr * 64 + i * 16 + l16) * 64 + col]);
#pragma unroll
            for (int j = 0; j < 4; j++)
                bfr[j] = *reinterpret_cast<const short8*>(&sB[(wc * 64 + j * 16 + l16) * 64 + col]);
#pragma unroll
            for (int i = 0; i < 4; i++)
#pragma unroll
                for (int j = 0; j < 4; j++)
                    acc[i][j] = __builtin_amdgcn_mfma_f32_16x16x32_bf16(af[i], bfr[j], acc[i][j], 0, 0, 0);
        }
    }
    __syncthreads();   // all sA/sB reads done; safe to overlay

    // ---- epilogue: P = exp(k) -> Pl, den partials; V -> Vl (m rows 0..127 = k, 128..255 = v) ----
    if (wr < 2) {
#pragma unroll
        for (int i = 0; i < 4; i++) {
            int rbase = wr * 64 + i * 16 + lq * 4;
            float srow[4] = {0.f, 0.f, 0.f, 0.f};
#pragma unroll
            for (int j = 0; j < 4; j++) {
                int n = wc * 64 + j * 16 + l16;
#pragma unroll
                for (int rr = 0; rr < 4; rr++) {
                    float e = __expf(acc[i][j][rr]);
                    Pl[(rbase + rr) * 136 + n] = f2bf(e);
                    srow[rr] += e;
                }
            }
#pragma unroll
            for (int rr = 0; rr < 4; rr++) {
                float s = srow[rr];
                s += __shfl_xor(s, 1, 64); s += __shfl_xor(s, 2, 64);
                s += __shfl_xor(s, 4, 64); s += __shfl_xor(s, 8, 64);
                if (l16 == 0) dpart[(rbase + rr) * 2 + wc] = s;
            }
        }
    } else {
#pragma unroll
        for (int i = 0; i < 4; i++) {
            int rbase = (wr - 2) * 64 + i * 16 + lq * 4;
#pragma unroll
            for (int j = 0; j < 4; j++) {
                int n = wc * 64 + j * 16 + l16;
#pragma unroll
                for (int rr = 0; rr < 4; rr++)
                    Vl[(rbase + rr) * 136 + n] = f2bf(acc[i][j][rr]);
            }
        }
    }
    __syncthreads();

    // ---- ctx GEMM: per head h: C_part[d][e] = sum_n P[h*32+d][n] * V[h*32+e][n] (K=128) ----
    int h = wv >> 1, eh = wv & 1;
    f32x4 a2[2];
    a2[0] = (f32x4){0.f, 0.f, 0.f, 0.f};
    a2[1] = (f32x4){0.f, 0.f, 0.f, 0.f};
#pragma unroll
    for (int kk = 0; kk < 4; kk++) {
        int col = kk * 32 + lq * 8;
        short8 bfr = *reinterpret_cast<const short8*>(&Vl[(h * 32 + eh * 16 + l16) * 136 + col]);
#pragma unroll
        for (int i = 0; i < 2; i++) {
            short8 af = *reinterpret_cast<const short8*>(&Pl[(h * 32 + i * 16 + l16) * 136 + col]);
            a2[i] = __builtin_amdgcn_mfma_f32_16x16x32_bf16(af, bfr, a2[i], 0, 0, 0);
        }
    }
    float* pp = part + ((size_t)(b * 32 + nt) * 4 + h) * 1024;
#pragma unroll
    for (int i = 0; i < 2; i++)
#pragma unroll
        for (int rr = 0; rr < 4; rr++)
            pp[(i * 16 + lq * 4 + rr) * 32 + eh * 16 + l16] = a2[i][rr];

    if (t < 128)
        denp[((size_t)b * 128 + t) * 32 + nt] = dpart[t * 2] + dpart[t * 2 + 1];
}

// ---------------- K2: reduce 32 ctx partials + divide by den -> C[bh][d][e] fp32 ----------------
// grid (bh=64, seg=4): each block handles 256 de of the 1024-slab. nt-ascending order.
__global__ __launch_bounds__(256) void k_red(const float* __restrict__ part,
                                             const float* __restrict__ denp,
                                             float* __restrict__ C) {
    __shared__ float invd[32];
    int bh = blockIdx.x, seg = blockIdx.y;
    int b = bh >> 2, h = bh & 3;
    int t = threadIdx.x;
    if (t < 32) {
        const float* dp = denp + ((size_t)b * 128 + h * 32 + t) * 32;
        float s = 0.f;
#pragma unroll
        for (int nt = 0; nt < 32; nt++) s += dp[nt];
        invd[t] = 1.0f / s;
    }
    __syncthreads();
    int de = seg * 256 + t;               // [0, 1024) -- in range
    float a = 0.f;
#pragma unroll 8
    for (int nt = 0; nt < 32; nt++)
        a += part[((size_t)(b * 32 + nt) * 4 + h) * 1024 + de];
    C[(size_t)bh * 1024 + de] = a * invd[de >> 5];
}

// ---------------- K3: G[b] = W_out . C_bd[b] . W_q  -> bf16 (W_q read as bf16 from Wb) --------
// grid (b=16, ot=16, ch=2): 16 o-rows per block, 128 c columns per block.
__global__ __launch_bounds__(256) void k_G(const float* __restrict__ C,
                                           const float* __restrict__ Wout,
                                           const u16* __restrict__ Wb,   // rows 0..127 = W_q bf16
                                           u16* __restrict__ Gb) {
    __shared__ float Cs[4096];    // [h][d][e]
    __shared__ float Us[2048];    // [ol][he]
    int b = blockIdx.x, ot = blockIdx.y, ch = blockIdx.z, t = threadIdx.x;
    int o0 = ot * 16;
#pragma unroll
    for (int q = 0; q < 16; q++) {
        int idx = q * 256 + t;
        Cs[idx] = C[(size_t)b * 4096 + idx];
    }
    __syncthreads();
#pragma unroll
    for (int q = 0; q < 8; q++) {
        int idx = q * 256 + t;          // ol*128 + he
        int ol = idx >> 7, he = idx & 127;
        int h = he >> 5, e = he & 31;
        const float* wrow = Wout + (o0 + ol) * 128 + h * 32;
        const float* crow = &Cs[h * 1024 + e];
        float a = 0.f;
#pragma unroll
        for (int d = 0; d < 32; d++) a += wrow[d] * crow[d * 32];
        Us[idx] = a;
    }
    __syncthreads();
    int ol = t >> 4, c0 = ch * 128 + (t & 15) * 8;
    float acc[8];
#pragma unroll
    for (int cc = 0; cc < 8; cc++) acc[cc] = 0.f;
    const float* Ur = &Us[ol * 128];
#pragma unroll 4
    for (int he = 0; he < 128; he++) {
        float u = Ur[he];
        short8 w8 = *reinterpret_cast<const short8*>(Wb + he * 256 + c0);
#pragma unroll
        for (int e = 0; e < 8; e++)
            acc[e] += u * bf2f((u16)w8[e]);
    }
    alignas(16) u16 ob[8];
#pragma unroll
    for (int cc = 0; cc < 8; cc++) ob[cc] = f2bf(acc[cc]);
    *reinterpret_cast<uint4*>(Gb + (size_t)(b * 256 + o0 + ol) * 256 + c0) =
        *reinterpret_cast<const uint4*>(ob);
}

// ---------------- K4: y = G[b].x + bias, BM=256 x BN=128, K=256, xT slab read ONCE ----------
// grid (nt=32, b=16), 512 threads (8 waves, 4M x 2N).
__global__ __launch_bounds__(512, 4) void k_y(const u16* __restrict__ Gb,
                                              const u16* __restrict__ xT,
                                              const float* __restrict__ bout,
                                              float* __restrict__ y) {
    __shared__ alignas(16) u16 sA[256 * 64];
    __shared__ alignas(16) u16 sB[128 * 64];
    int t = threadIdx.x;
    int nt = blockIdx.x, b = blockIdx.y;
    int n0 = nt * 128;
    int lane = t & 63, wv = t >> 6, l16 = lane & 15, lq = lane >> 4;
    int wr = wv >> 1, wc = wv & 1;
    int trow = t >> 3, tc8 = (t & 7) * 8;

    f32x4 acc[4][4];
#pragma unroll
    for (int i = 0; i < 4; i++)
#pragma unroll
        for (int j = 0; j < 4; j++) acc[i][j] = (f32x4){0.f, 0.f, 0.f, 0.f};

    const u16* Asrc = Gb + (size_t)b * 256 * 256;
    const u16* Bsrc = xT + (size_t)(b * 4096 + n0) * 256;

    for (int kc = 0; kc < 4; kc++) {
        __syncthreads();
#pragma unroll
        for (int q = 0; q < 4; q++) {       // A: 256 rows x 64 c (linear in t)
            int row = q * 64 + trow;
            gload16(Asrc + (size_t)row * 256 + kc * 64 + tc8, &sA[row * 64 + tc8]);
        }
#pragma unroll
        for (int q = 0; q < 2; q++) {       // B: 128 rows x 64 c
            int row = q * 64 + trow;
            gload16(Bsrc + (size_t)row * 256 + kc * 64 + tc8, &sB[row * 64 + tc8]);
        }
        __syncthreads();
#pragma unroll
        for (int ks = 0; ks < 2; ks++) {
            int col = ks * 32 + lq * 8;
            short8 af[4], bfr[4];
#pragma unroll
            for (int i = 0; i < 4; i++)
                af[i] = *reinterpret_cast<const short8*>(&sA[(wr * 64 + i * 16 + l16) * 64 + col]);
#pragma unroll
            for (int j = 0; j < 4; j++)
                bfr[j] = *reinterpret_cast<const short8*>(&sB[(wc * 64 + j * 16 + l16) * 64 + col]);
#pragma unroll
            for (int i = 0; i < 4; i++)
#pragma unroll
                for (int j = 0; j < 4; j++)
                    acc[i][j] = __builtin_amdgcn_mfma_f32_16x16x32_bf16(af[i], bfr[j], acc[i][j], 0, 0, 0);
        }
    }
#pragma unroll
    for (int i = 0; i < 4; i++) {
        int obase = wr * 64 + i * 16 + lq * 4;
#pragma unroll
        for (int j = 0; j < 4; j++) {
            int n = n0 + wc * 64 + j * 16 + l16;
#pragma unroll
            for (int rr = 0; rr < 4; rr++) {
                int o = obase + rr;
                y[(size_t)(b * 256 + o) * 4096 + n] = acc[i][j][rr] + bout[o];
            }
        }
    }
}

extern "C" void kernel_launch(void* const* d_in, const int* in_sizes, int n_in,
                              void* d_out, int out_size, void* d_ws, size_t ws_size,
                              hipStream_t stream) {
    const float* x    = (const float*)d_in[0];
    const float* Wqkv = (const float*)d_in[1];
    const float* Wout = (const float*)d_in[2];
    const float* bout = (const float*)d_in[3];
    float* y = (float*)d_out;

    char* ws = (char*)d_ws;
    u16*   xT   = (u16*)(ws);                     // 32 MB   [b][n][c] bf16
    float* part = (float*)(ws + 33554432);        // 8 MB    ctx partials [b][nt][h][1024]
    float* denp = (float*)(ws + 41943040);        // 256 KB  den partials [b*128+row][nt]
    float* C    = (float*)(ws + 42205184);        // 256 KB  [bh][d][e] fp32
    u16*   Gb   = (u16*)(ws + 42467328);          // 2 MB    [b][256][256] bf16
    u16*   Wb   = (u16*)(ws + 44564480);          // 192 KB  W_qkv bf16 (all 384 rows)

    k_transpose<<<dim3(64, 4, 16), 256, 0, stream>>>(x, xT, Wqkv, Wb);
    k_fused    <<<dim3(32, 16), 512, 0, stream>>>(xT, Wb, part, denp);
    k_red      <<<dim3(64, 4), 256, 0, stream>>>(part, denp, C);
    k_G        <<<dim3(16, 16, 2), 256, 0, stream>>>(C, Wout, Wb, Gb);
    k_y        <<<dim3(32, 16), 512, 0, stream>>>(Gb, xT, bout, y);
}